// Round 2
// baseline (162.194 us; speedup 1.0000x reference)
//
#include <hip/hip_runtime.h>

#define WI 512
#define HI 512
#define WO 2048
#define HO 2048
#define NIMG 8
#define CCH 3
#define EPS 1e-8f
#define ROWS 4

// ===========================================================================
// Table kernel: for every (image n, output coordinate pos) precompute the
// 1-D bilinear entry {w0, w1, off0, off1} for both axes.
//   x-axis entries: off = clamped src column
//   y-axis entries: off = clamped src row * WI  (premultiplied)
// Weights are already multiplied by validity (zeros padding), so
// mask = (wy0+wy1)*(wx0+wx1) exactly as in the reference.
// Each thread computes its own image's sigmoid params (4 expf) - trivial.
// ===========================================================================
__global__ void diffcomp_tables(const float* __restrict__ coor,
                                int4* __restrict__ xtab,
                                int4* __restrict__ ytab) {
    const int idx = blockIdx.x * 256 + threadIdx.x;    // [0, 2*NIMG*2048)
    const bool isY = idx >= NIMG * WO;
    const int rem = isY ? idx - NIMG * WO : idx;
    const int n   = rem >> 11;            // / 2048
    const int pos = rem & 2047;           // % 2048

    const float cx = coor[n * 4 + 0];
    const float cy = coor[n * 4 + 1];
    const float cw = coor[n * 4 + 2];
    const float ch = coor[n * 4 + 3];

    float a, t, INF;
    if (!isY) {
        const float x = (1.0f / (1.0f + expf(-cx))) * (float)WO;
        const float w = (1.0f / (1.0f + expf(-cw))) * (float)WO;
        a = (float)WO / (w + EPS);
        t = (2.0f / (float)WO) * ((float)WO * 0.5f - x) * a;
        INF = (float)WI;
    } else {
        const float y = (1.0f / (1.0f + expf(-cy))) * (float)HO;
        const float h = (1.0f / (1.0f + expf(-ch))) * (float)HO;
        a = (float)HO / (h + EPS);
        t = (2.0f / (float)HO) * ((float)HO * 0.5f - y) * a;
        INF = (float)HI;
    }

    const float s  = (2.0f * (float)pos + 1.0f) / 2048.0f - 1.0f;
    const float g  = a * s + t;
    const float ic = ((g + 1.0f) * INF - 1.0f) * 0.5f;
    const float f0 = floorf(ic);
    const float fr1 = ic - f0;
    const float fr0 = 1.0f - fr1;
    const float f1 = f0 + 1.0f;
    const float v0 = (f0 >= 0.0f && f0 < INF) ? 1.0f : 0.0f;
    const float v1 = (f1 >= 0.0f && f1 < INF) ? 1.0f : 0.0f;
    const float w0 = fr0 * v0;
    const float w1 = fr1 * v1;
    int c0 = (int)fminf(fmaxf(f0, 0.0f), INF - 1.0f);
    int c1 = (int)fminf(fmaxf(f1, 0.0f), INF - 1.0f);
    if (isY) { c0 *= WI; c1 *= WI; }

    int4 e;
    e.x = __float_as_int(w0);
    e.y = __float_as_int(w1);
    e.z = c0;
    e.w = c1;
    (isY ? ytab : xtab)[(n << 11) + pos] = e;
}

// ===========================================================================
// Main kernel (table version): tile = 256 wo x ROWS ho. One thread/column.
// X entries: 8 coalesced int4 loads into registers.
// Y entries for the block's rows: 512 B LDS slab, broadcast ds_read per row.
// Gathers + blend skipped where mask == 0 (bit-exact skip).
// ===========================================================================
__launch_bounds__(256)
__global__ void diffcomp_main2(const float* __restrict__ src,
                               const float* __restrict__ bg,
                               const int4* __restrict__ xtab,
                               const int4* __restrict__ ytab,
                               float* __restrict__ out) {
    __shared__ int4 ylds[ROWS * NIMG];

    const int tid = threadIdx.x;
    const int wo  = blockIdx.x * 256 + tid;
    const int ho0 = blockIdx.y * ROWS;

    if (tid < ROWS * NIMG) {
        const int r = tid >> 3;       // NIMG == 8
        const int n = tid & 7;
        ylds[tid] = ytab[(n << 11) + ho0 + r];
    }

    float wx0[NIMG], wx1[NIMG], mxv[NIMG];
    int   ox0[NIMG], ox1[NIMG];
#pragma unroll
    for (int n = 0; n < NIMG; n++) {
        const int4 e = xtab[(n << 11) + wo];
        wx0[n] = __int_as_float(e.x);
        wx1[n] = __int_as_float(e.y);
        ox0[n] = e.z;
        ox1[n] = e.w;
        mxv[n] = wx0[n] + wx1[n];
    }

    __syncthreads();

    for (int r = 0; r < ROWS; r++) {
        const int ho  = ho0 + r;
        const int pix = ho * WO + wo;

        float acc0 = bg[0 * HO * WO + pix];
        float acc1 = bg[1 * HO * WO + pix];
        float acc2 = bg[2 * HO * WO + pix];

#pragma unroll
        for (int n = 0; n < NIMG; n++) {
            const int4 ey = ylds[r * NIMG + n];
            const float wy0 = __int_as_float(ey.x);
            const float wy1 = __int_as_float(ey.y);
            const float m = (wy0 + wy1) * mxv[n];
            if (m > 0.0f) {
                const float* ib = src + n * (CCH * HI * WI);
                const int o00 = ey.z + ox0[n];
                const int o01 = ey.z + ox1[n];
                const int o10 = ey.w + ox0[n];
                const int o11 = ey.w + ox1[n];
                const float om = 1.0f - m;
                float s0, s1, s2;
                {
                    const float* p = ib + 0 * HI * WI;
                    const float v00 = p[o00], v01 = p[o01], v10 = p[o10], v11 = p[o11];
                    s0 = (v00 * wy0 + v10 * wy1) * wx0[n]
                       + (v01 * wy0 + v11 * wy1) * wx1[n];
                }
                {
                    const float* p = ib + 1 * HI * WI;
                    const float v00 = p[o00], v01 = p[o01], v10 = p[o10], v11 = p[o11];
                    s1 = (v00 * wy0 + v10 * wy1) * wx0[n]
                       + (v01 * wy0 + v11 * wy1) * wx1[n];
                }
                {
                    const float* p = ib + 2 * HI * WI;
                    const float v00 = p[o00], v01 = p[o01], v10 = p[o10], v11 = p[o11];
                    s2 = (v00 * wy0 + v10 * wy1) * wx0[n]
                       + (v01 * wy0 + v11 * wy1) * wx1[n];
                }
                acc0 = acc0 * om + s0 * m;
                acc1 = acc1 * om + s1 * m;
                acc2 = acc2 * om + s2 * m;
            }
        }

        out[0 * HO * WO + pix] = acc0;
        out[1 * HO * WO + pix] = acc1;
        out[2 * HO * WO + pix] = acc2;
    }
}

// ===========================================================================
// Fallback path (round-1 kernels) if ws_size can't hold the tables.
// ===========================================================================
__global__ void diffcomp_params(const float* __restrict__ coor,
                                float4* __restrict__ params) {
    int n = threadIdx.x;
    if (n < NIMG) {
        float cx = coor[n * 4 + 0];
        float cy = coor[n * 4 + 1];
        float cw = coor[n * 4 + 2];
        float ch = coor[n * 4 + 3];
        float x = (1.0f / (1.0f + expf(-cx))) * (float)WO;
        float y = (1.0f / (1.0f + expf(-cy))) * (float)HO;
        float w = (1.0f / (1.0f + expf(-cw))) * (float)WO;
        float h = (1.0f / (1.0f + expf(-ch))) * (float)HO;
        float a  = (float)WO / (w + EPS);
        float tx = (2.0f / (float)WO) * ((float)WO * 0.5f - x) * a;
        float b  = (float)HO / (h + EPS);
        float ty = (2.0f / (float)HO) * ((float)HO * 0.5f - y) * b;
        params[n] = make_float4(a, tx, b, ty);
    }
}

__launch_bounds__(256)
__global__ void diffcomp_main(const float* __restrict__ src,
                              const float* __restrict__ bg,
                              const float4* __restrict__ params,
                              float* __restrict__ out) {
    const int wo  = blockIdx.x * 256 + threadIdx.x;
    const int ho0 = blockIdx.y * 8;

    float4 P[NIMG];
#pragma unroll
    for (int n = 0; n < NIMG; n++) P[n] = params[n];

    float wxv0[NIMG], wxv1[NIMG], mx[NIMG];
    int   x0c[NIMG], x1c[NIMG];
    const float xs = (2.0f * (float)wo + 1.0f) / (float)WO - 1.0f;
#pragma unroll
    for (int n = 0; n < NIMG; n++) {
        float a  = P[n].x, tx = P[n].y;
        float gx = a * xs + tx;
        float ix = (((gx + 1.0f) * (float)WI) - 1.0f) * 0.5f;
        float x0f = floorf(ix);
        float wx1 = ix - x0f;
        float wx0 = 1.0f - wx1;
        float x1f = x0f + 1.0f;
        float vx0 = (x0f >= 0.0f && x0f < (float)WI) ? 1.0f : 0.0f;
        float vx1 = (x1f >= 0.0f && x1f < (float)WI) ? 1.0f : 0.0f;
        wxv0[n] = wx0 * vx0;
        wxv1[n] = wx1 * vx1;
        x0c[n] = (int)fminf(fmaxf(x0f, 0.0f), (float)(WI - 1));
        x1c[n] = (int)fminf(fmaxf(x1f, 0.0f), (float)(WI - 1));
        mx[n] = wxv0[n] + wxv1[n];
    }

    for (int r = 0; r < 8; r++) {
        const int ho = ho0 + r;
        const float ys = (2.0f * (float)ho + 1.0f) / (float)HO - 1.0f;
        const int pix = ho * WO + wo;

        float acc0 = bg[0 * HO * WO + pix];
        float acc1 = bg[1 * HO * WO + pix];
        float acc2 = bg[2 * HO * WO + pix];

#pragma unroll
        for (int n = 0; n < NIMG; n++) {
            float b  = P[n].z, ty = P[n].w;
            float gy = b * ys + ty;
            float iy = (((gy + 1.0f) * (float)HI) - 1.0f) * 0.5f;
            float y0f = floorf(iy);
            float wy1 = iy - y0f;
            float wy0 = 1.0f - wy1;
            float y1f = y0f + 1.0f;
            float vy0 = (y0f >= 0.0f && y0f < (float)HI) ? 1.0f : 0.0f;
            float vy1 = (y1f >= 0.0f && y1f < (float)HI) ? 1.0f : 0.0f;
            float wyv0 = wy0 * vy0;
            float wyv1 = wy1 * vy1;
            float m = (wyv0 + wyv1) * mx[n];
            if (m > 0.0f) {
                int y0i = (int)fminf(fmaxf(y0f, 0.0f), (float)(HI - 1));
                int y1i = (int)fminf(fmaxf(y1f, 0.0f), (float)(HI - 1));
                const float* ib = src + n * (CCH * HI * WI);
                const int o00 = y0i * WI + x0c[n];
                const int o01 = y0i * WI + x1c[n];
                const int o10 = y1i * WI + x0c[n];
                const int o11 = y1i * WI + x1c[n];
                const float om = 1.0f - m;
                float s0, s1, s2;
                {
                    const float* p = ib + 0 * HI * WI;
                    float v00 = p[o00], v01 = p[o01], v10 = p[o10], v11 = p[o11];
                    s0 = (v00 * wyv0 + v10 * wyv1) * wxv0[n]
                       + (v01 * wyv0 + v11 * wyv1) * wxv1[n];
                }
                {
                    const float* p = ib + 1 * HI * WI;
                    float v00 = p[o00], v01 = p[o01], v10 = p[o10], v11 = p[o11];
                    s1 = (v00 * wyv0 + v10 * wyv1) * wxv0[n]
                       + (v01 * wyv0 + v11 * wyv1) * wxv1[n];
                }
                {
                    const float* p = ib + 2 * HI * WI;
                    float v00 = p[o00], v01 = p[o01], v10 = p[o10], v11 = p[o11];
                    s2 = (v00 * wyv0 + v10 * wyv1) * wxv0[n]
                       + (v01 * wyv0 + v11 * wyv1) * wxv1[n];
                }
                acc0 = acc0 * om + s0 * m;
                acc1 = acc1 * om + s1 * m;
                acc2 = acc2 * om + s2 * m;
            }
        }

        out[0 * HO * WO + pix] = acc0;
        out[1 * HO * WO + pix] = acc1;
        out[2 * HO * WO + pix] = acc2;
    }
}

extern "C" void kernel_launch(void* const* d_in, const int* in_sizes, int n_in,
                              void* d_out, int out_size, void* d_ws, size_t ws_size,
                              hipStream_t stream) {
    const float* src  = (const float*)d_in[0];   // [8,3,512,512]
    const float* bg   = (const float*)d_in[1];   // [1,3,2048,2048]
    const float* coor = (const float*)d_in[2];   // [8,4]
    float* out = (float*)d_out;                  // [1,3,2048,2048]

    const size_t tab_bytes = (size_t)2 * NIMG * 2048 * sizeof(int4); // 512 KB

    if (ws_size >= tab_bytes) {
        int4* xtab = (int4*)d_ws;
        int4* ytab = xtab + NIMG * 2048;
        // 2*8*2048 = 32768 entries -> 128 blocks x 256
        hipLaunchKernelGGL(diffcomp_tables, dim3(128), dim3(256), 0, stream,
                           coor, xtab, ytab);
        dim3 grid(WO / 256, HO / ROWS);
        hipLaunchKernelGGL(diffcomp_main2, grid, dim3(256), 0, stream,
                           src, bg, xtab, ytab, out);
    } else {
        float4* params = (float4*)d_ws;          // 128 B
        hipLaunchKernelGGL(diffcomp_params, dim3(1), dim3(64), 0, stream, coor, params);
        dim3 grid(WO / 256, HO / 8);
        hipLaunchKernelGGL(diffcomp_main, grid, dim3(256), 0, stream,
                           src, bg, params, out);
    }
}